// Round 2
// baseline (1360.832 us; speedup 1.0000x reference)
//
#include <hip/hip_runtime.h>
#include <cstddef>
#include <cstdint>

// B=2, NF=8(seq), DIM=128, HW=1600 -> Bp=3200 positions, M=25600 token rows
// HID=256, INNER=512, NH=128, DH=4

#define NPOS 3200
#define MTOK 25600

__device__ __forceinline__ float bf2f(unsigned short u) {
  union { uint32_t i; float f; } v; v.i = ((uint32_t)u) << 16; return v.f;
}
__device__ __forceinline__ unsigned short f2bf(float f) {
  union { float f; uint32_t i; } v; v.f = f;
  uint32_t r = (v.i + 0x7fffu + ((v.i >> 16) & 1u)) >> 16;
  return (unsigned short)r;
}
__device__ __forceinline__ float geluf(float x) {
  return 0.5f * x * (1.0f + erff(x * 0.70710678118654752f));
}
__device__ __forceinline__ float siluf(float x) {
  return x / (1.0f + expf(-x));
}

// ---------- transpose in: x (B,1024,1600) fp32 -> xflat (B*1600, 1024) bf16 ----------
__global__ __launch_bounds__(256) void trans_in(const float* __restrict__ x,
                                                unsigned short* __restrict__ xf) {
  __shared__ float tile[32][33];
  const int b = blockIdx.z;
  const int hw0 = blockIdx.x * 32;
  const int sc0 = blockIdx.y * 32;
  const int tx = threadIdx.x, ty = threadIdx.y;  // 32 x 8
#pragma unroll
  for (int i = 0; i < 32; i += 8)
    tile[ty + i][tx] = x[((size_t)b * 1024 + sc0 + ty + i) * 1600 + hw0 + tx];
  __syncthreads();
#pragma unroll
  for (int i = 0; i < 32; i += 8)
    xf[((size_t)b * 1600 + hw0 + ty + i) * 1024 + sc0 + tx] = f2bf(tile[tx][ty + i]);
}

// ---------- transpose out: out[b,sc,hw] = x[b,sc,hw] + o[(b*1600+hw)*1024 + sc] ----------
__global__ __launch_bounds__(256) void trans_out(const float* __restrict__ x,
                                                 const unsigned short* __restrict__ o,
                                                 float* __restrict__ out) {
  __shared__ float tile[32][33];
  const int b = blockIdx.z;
  const int hw0 = blockIdx.x * 32;
  const int sc0 = blockIdx.y * 32;
  const int tx = threadIdx.x, ty = threadIdx.y;
#pragma unroll
  for (int i = 0; i < 32; i += 8)
    tile[ty + i][tx] = bf2f(o[((size_t)b * 1600 + hw0 + ty + i) * 1024 + sc0 + tx]);
  __syncthreads();
#pragma unroll
  for (int i = 0; i < 32; i += 8) {
    size_t idx = ((size_t)b * 1024 + sc0 + ty + i) * 1600 + hw0 + tx;
    out[idx] = x[idx] + tile[tx][ty + i];
  }
}

// ---------- generic 64x64 tiled GEMM: C = epilogue(A @ W^T) ----------
// A: bf16 (AF32=0) or fp32 (AF32=1), (M x lda), uses K cols. W: fp32 (N x ldw).
// MODE 0: C_bf16 = v + bias
// MODE 1: C_bf16 = gelu(v + bias)
// MODE 2: C_f32[flip-mapped row] += v + bias   (down-proj + add-back)
// MODE 3: C_bf16 += v                          (accumulate, no bias)
// MODE 4: C_f32 = v + bias
template <int MODE, int AF32>
__global__ __launch_bounds__(256) void gemm_k(const void* __restrict__ Av, int lda,
                                              const float* __restrict__ Wt, int ldw,
                                              const float* __restrict__ bias,
                                              void* __restrict__ Cv, int ldc, int K,
                                              int flip) {
  __shared__ float As[16][64];
  __shared__ float Bs[16][64];
  const int bn = blockIdx.x * 64;
  const int bm = blockIdx.y * 64;
  const int t = threadIdx.x;
  const int tx = t & 15, ty = t >> 4;
  const int lr = t >> 2;        // 0..63
  const int lc = (t & 3) << 2;  // 0,4,8,12
  const float* Wp = Wt + (size_t)(bn + lr) * ldw + lc;
  float acc[4][4] = {};
  for (int k0 = 0; k0 < K; k0 += 16) {
    float a0, a1, a2, a3;
    if (AF32) {
      const float* Ap = (const float*)Av + (size_t)(bm + lr) * lda + lc + k0;
      float4 av = *(const float4*)Ap;
      a0 = av.x; a1 = av.y; a2 = av.z; a3 = av.w;
    } else {
      const unsigned short* Ap = (const unsigned short*)Av + (size_t)(bm + lr) * lda + lc + k0;
      ushort4 av = *(const ushort4*)Ap;
      a0 = bf2f(av.x); a1 = bf2f(av.y); a2 = bf2f(av.z); a3 = bf2f(av.w);
    }
    float4 wv = *(const float4*)(Wp + k0);
    As[lc + 0][lr] = a0; As[lc + 1][lr] = a1; As[lc + 2][lr] = a2; As[lc + 3][lr] = a3;
    Bs[lc + 0][lr] = wv.x; Bs[lc + 1][lr] = wv.y; Bs[lc + 2][lr] = wv.z; Bs[lc + 3][lr] = wv.w;
    __syncthreads();
#pragma unroll
    for (int k = 0; k < 16; ++k) {
      float4 a4 = *(const float4*)&As[k][ty << 2];
      float4 b4 = *(const float4*)&Bs[k][tx << 2];
      float av_[4] = {a4.x, a4.y, a4.z, a4.w};
      float bv_[4] = {b4.x, b4.y, b4.z, b4.w};
#pragma unroll
      for (int i = 0; i < 4; ++i)
#pragma unroll
        for (int j = 0; j < 4; ++j) acc[i][j] += av_[i] * bv_[j];
    }
    __syncthreads();
  }
#pragma unroll
  for (int i = 0; i < 4; ++i) {
    const int m = bm + (ty << 2) + i;
    const int cn = bn + (tx << 2);
    if (MODE == 0 || MODE == 1) {
      unsigned short* Crow = (unsigned short*)Cv + (size_t)m * ldc + cn;
      ushort4 o;
      float v0 = acc[i][0] + bias[cn + 0];
      float v1 = acc[i][1] + bias[cn + 1];
      float v2 = acc[i][2] + bias[cn + 2];
      float v3 = acc[i][3] + bias[cn + 3];
      if (MODE == 1) { v0 = geluf(v0); v1 = geluf(v1); v2 = geluf(v2); v3 = geluf(v3); }
      o.x = f2bf(v0); o.y = f2bf(v1); o.z = f2bf(v2); o.w = f2bf(v3);
      *(ushort4*)Crow = o;
    } else if (MODE == 3) {
      unsigned short* Crow = (unsigned short*)Cv + (size_t)m * ldc + cn;
      ushort4 old = *(const ushort4*)Crow;
      ushort4 o;
      o.x = f2bf(bf2f(old.x) + acc[i][0]);
      o.y = f2bf(bf2f(old.y) + acc[i][1]);
      o.z = f2bf(bf2f(old.z) + acc[i][2]);
      o.w = f2bf(bf2f(old.w) + acc[i][3]);
      *(ushort4*)Crow = o;
    } else if (MODE == 2) {
      const int p = m >> 3, s = m & 7;
      const int fs = flip ? (7 - s) : s;
      float* Crow = (float*)Cv + (size_t)(p * 8 + fs) * ldc + cn;
      float4 old = *(const float4*)Crow;
      float4 o;
      o.x = old.x + acc[i][0] + bias[cn + 0];
      o.y = old.y + acc[i][1] + bias[cn + 1];
      o.z = old.z + acc[i][2] + bias[cn + 2];
      o.w = old.w + acc[i][3] + bias[cn + 3];
      *(float4*)Crow = o;
    } else {  // MODE 4
      float* Crow = (float*)Cv + (size_t)m * ldc + cn;
      float4 o;
      o.x = acc[i][0] + bias[cn + 0];
      o.y = acc[i][1] + bias[cn + 1];
      o.z = acc[i][2] + bias[cn + 2];
      o.w = acc[i][3] + bias[cn + 3];
      *(float4*)Crow = o;
    }
  }
}

// ---------- layernorm with flip-on-read: y bf16 ----------
__global__ __launch_bounds__(64) void ln_k(const float* __restrict__ h,
                                           const float* __restrict__ w,
                                           const float* __restrict__ b,
                                           unsigned short* __restrict__ y, int flip) {
  const int m = blockIdx.x;
  const int p = m >> 3, s = m & 7;
  const int ss = flip ? (7 - s) : s;
  const float* row = h + (size_t)(p * 8 + ss) * 256;
  const int lane = threadIdx.x;
  float4 v = *(const float4*)(row + lane * 4);
  float sum = v.x + v.y + v.z + v.w;
  float sq = v.x * v.x + v.y * v.y + v.z * v.z + v.w * v.w;
#pragma unroll
  for (int o = 32; o > 0; o >>= 1) {
    sum += __shfl_xor(sum, o);
    sq += __shfl_xor(sq, o);
  }
  float mu = sum * (1.f / 256.f);
  float var = sq * (1.f / 256.f) - mu * mu;
  float r = rsqrtf(var + 1e-5f);
  float4 wv = *(const float4*)(w + lane * 4);
  float4 bv = *(const float4*)(b + lane * 4);
  ushort4 o_;
  o_.x = f2bf((v.x - mu) * r * wv.x + bv.x);
  o_.y = f2bf((v.y - mu) * r * wv.y + bv.y);
  o_.z = f2bf((v.z - mu) * r * wv.z + bv.z);
  o_.w = f2bf((v.w - mu) * r * wv.w + bv.w);
  *(ushort4*)(y + (size_t)m * 256 + lane * 4) = o_;
}

// ---------- causal depthwise conv(4) + silu: xm bf16 -> xa bf16 ----------
__global__ __launch_bounds__(512) void conv_k(const unsigned short* __restrict__ xm,
                                              const float* __restrict__ cw,
                                              const float* __restrict__ cb,
                                              unsigned short* __restrict__ xa) {
  const int p = blockIdx.x;
  const int c = threadIdx.x;
  float v[8];
#pragma unroll
  for (int s = 0; s < 8; ++s) v[s] = bf2f(xm[(size_t)(p * 8 + s) * 512 + c]);
  const float4 cwv = *(const float4*)(cw + c * 4);
  const float cbv = cb[c];
#pragma unroll
  for (int s = 0; s < 8; ++s) {
    float acc = cbv + v[s] * cwv.w;
    if (s >= 1) acc += v[s - 1] * cwv.z;
    if (s >= 2) acc += v[s - 2] * cwv.y;
    if (s >= 3) acc += v[s - 3] * cwv.x;
    xa[(size_t)(p * 8 + s) * 512 + c] = f2bf(siluf(acc));
  }
}

// ---------- fold gate weights: Wfold[g][j][n*4+d] ----------
__global__ __launch_bounds__(256) void fold_k(const float* __restrict__ igw,
                                              const float* __restrict__ fgw,
                                              const float* __restrict__ qw,
                                              const float* __restrict__ kw,
                                              float* __restrict__ wfold) {
  const int tid = blockIdx.x * 256 + threadIdx.x;  // 65536
  const int j = tid >> 9;
  const int c = tid & 511;
  const int n = c >> 2, d = c & 3;
  float si = 0.f, sf = 0.f;
#pragma unroll
  for (int e = 0; e < 4; ++e) {
    const float qv = qw[n * 16 + e * 4 + d];
    const float kv = kw[n * 16 + e * 4 + d];
    si += igw[j * 1536 + n * 4 + e] * qv + igw[j * 1536 + 512 + n * 4 + e] * kv;
    sf += fgw[j * 1536 + n * 4 + e] * qv + fgw[j * 1536 + 512 + n * 4 + e] * kv;
  }
  wfold[j * 512 + c] = si;
  wfold[65536 + j * 512 + c] = sf;
}

// ---------- mLSTM (q/k proj fused) + head-LN + skip + z-gate ----------
// thread (p, n): owns head n of position p. Overwrites xa with gated output.
__global__ __launch_bounds__(128) void mlstm_k(unsigned short* __restrict__ xab,
                                               const unsigned short* __restrict__ xmb,
                                               const unsigned short* __restrict__ zb,
                                               const unsigned short* __restrict__ igb,
                                               const unsigned short* __restrict__ fgb,
                                               const float* __restrict__ qw,
                                               const float* __restrict__ kw,
                                               const float* __restrict__ onw,
                                               const float* __restrict__ onb,
                                               const float* __restrict__ skp) {
  const int p = blockIdx.x;
  const int n = threadIdx.x;
  float qwv[4][4], kwv[4][4];
#pragma unroll
  for (int e = 0; e < 4; ++e) {
    float4 q4 = *(const float4*)(qw + n * 16 + e * 4);
    float4 k4 = *(const float4*)(kw + n * 16 + e * 4);
    qwv[e][0] = q4.x; qwv[e][1] = q4.y; qwv[e][2] = q4.z; qwv[e][3] = q4.w;
    kwv[e][0] = k4.x; kwv[e][1] = k4.y; kwv[e][2] = k4.z; kwv[e][3] = k4.w;
  }
  float xa[8][4], q[8][4], k[8][4], v[8][4], lfc[8], ig[8];
  float run = 0.f;
#pragma unroll
  for (int s = 0; s < 8; ++s) {
    const size_t row = (size_t)(p * 8 + s);
    ushort4 xa4 = *(const ushort4*)(xab + row * 512 + n * 4);
    xa[s][0] = bf2f(xa4.x); xa[s][1] = bf2f(xa4.y); xa[s][2] = bf2f(xa4.z); xa[s][3] = bf2f(xa4.w);
    ushort4 v4 = *(const ushort4*)(xmb + row * 512 + n * 4);
    v[s][0] = bf2f(v4.x); v[s][1] = bf2f(v4.y); v[s][2] = bf2f(v4.z); v[s][3] = bf2f(v4.w);
#pragma unroll
    for (int e = 0; e < 4; ++e) {
      q[s][e] = xa[s][0] * qwv[e][0] + xa[s][1] * qwv[e][1] + xa[s][2] * qwv[e][2] + xa[s][3] * qwv[e][3];
      k[s][e] = xa[s][0] * kwv[e][0] + xa[s][1] * kwv[e][1] + xa[s][2] * kwv[e][2] + xa[s][3] * kwv[e][3];
    }
    ig[s] = bf2f(igb[row * 128 + n]);
    const float f = bf2f(fgb[row * 128 + n]);
    const float ls = (f > 0.f) ? -log1pf(expf(-f)) : (f - log1pf(expf(f)));
    run += ls;
    lfc[s] = run;
  }
  const float4 onwv = *(const float4*)(onw + n * 4);
  const float4 onbv = *(const float4*)(onb + n * 4);
  const float4 skv = *(const float4*)(skp + n * 4);
#pragma unroll
  for (int s = 0; s < 8; ++s) {
    float crow[8];
    float mx = -1e30f;
#pragma unroll
    for (int t = 0; t < 8; ++t)
      if (t <= s) {
        const float ld = lfc[s] - lfc[t] + ig[t];
        crow[t] = ld;
        mx = fmaxf(mx, ld);
      }
    float csum = 0.f;
#pragma unroll
    for (int t = 0; t < 8; ++t)
      if (t <= s) {
        const float dm = expf(crow[t] - mx);
        const float qkd = (q[s][0] * k[t][0] + q[s][1] * k[t][1] + q[s][2] * k[t][2] + q[s][3] * k[t][3]) * 0.5f;
        crow[t] = qkd * dm;
        csum += crow[t];
      }
    const float inv = 1.f / (fmaxf(fabsf(csum), expf(-mx)) + 1e-6f);
    float o0 = 0, o1 = 0, o2 = 0, o3 = 0;
#pragma unroll
    for (int t = 0; t < 8; ++t)
      if (t <= s) {
        const float cn = crow[t];
        o0 += cn * v[t][0]; o1 += cn * v[t][1]; o2 += cn * v[t][2]; o3 += cn * v[t][3];
      }
    o0 *= inv; o1 *= inv; o2 *= inv; o3 *= inv;
    const float mu = 0.25f * (o0 + o1 + o2 + o3);
    const float d0 = o0 - mu, d1 = o1 - mu, d2 = o2 - mu, d3 = o3 - mu;
    const float var = 0.25f * (d0 * d0 + d1 * d1 + d2 * d2 + d3 * d3);
    const float r = rsqrtf(var + 1e-5f);
    const size_t row = (size_t)(p * 8 + s);
    ushort4 z4 = *(const ushort4*)(zb + row * 512 + n * 4);
    ushort4 ge;
    ge.x = f2bf((d0 * r * onwv.x + onbv.x + skv.x * xa[s][0]) * siluf(bf2f(z4.x)));
    ge.y = f2bf((d1 * r * onwv.y + onbv.y + skv.y * xa[s][1]) * siluf(bf2f(z4.y)));
    ge.z = f2bf((d2 * r * onwv.z + onbv.z + skv.z * xa[s][2]) * siluf(bf2f(z4.z)));
    ge.w = f2bf((d3 * r * onwv.w + onbv.w + skv.w * xa[s][3]) * siluf(bf2f(z4.w)));
    *(ushort4*)(xab + row * 512 + n * 4) = ge;
  }
}

extern "C" void kernel_launch(void* const* d_in, const int* in_sizes, int n_in,
                              void* d_out, int out_size, void* d_ws, size_t ws_size,
                              hipStream_t stream) {
  const float* x = (const float*)d_in[0];
  const float* fc1w = (const float*)d_in[1];
  const float* fc1b = (const float*)d_in[2];
  const float* fc2w = (const float*)d_in[3];
  const float* fc2b = (const float*)d_in[4];
  const float* ofc1w = (const float*)d_in[5];
  const float* ofc1b = (const float*)d_in[6];
  const float* ofc2w = (const float*)d_in[7];
  const float* ofc2b = (const float*)d_in[8];
  const float* nw = (const float*)d_in[9];
  const float* nb = (const float*)d_in[10];
  const float* upw = (const float*)d_in[11];
  const float* upb = (const float*)d_in[12];
  const float* cw = (const float*)d_in[13];
  const float* cb = (const float*)d_in[14];
  const float* qw = (const float*)d_in[15];
  const float* kw = (const float*)d_in[16];
  const float* igw = (const float*)d_in[17];
  const float* igbias = (const float*)d_in[18];
  const float* fgw = (const float*)d_in[19];
  const float* fgbias = (const float*)d_in[20];
  const float* onw = (const float*)d_in[21];
  const float* onb = (const float*)d_in[22];
  const float* skp = (const float*)d_in[23];
  const float* dww = (const float*)d_in[24];
  const float* dwb = (const float*)d_in[25];
  float* out = (float*)d_out;

  // workspace layout (byte offsets), total ~132 MB
  char* ws = (char*)d_ws;
  float* hbuf = (float*)ws;                                    // M*256 f32   26,214,400 B
  unsigned short* bufD = (unsigned short*)(ws + 26214400);     // M*256 bf16  13,107,200 B
  unsigned short* bufA = (unsigned short*)(ws + 39321600);     // M*128 bf16   6,553,600 B
  unsigned short* fgb = (unsigned short*)(ws + 45875200);      // M*128 bf16   6,553,600 B (aliases xflat)
  unsigned short* xflat = fgb;                                 // M*128 bf16 (dead after fc1)
  unsigned short* xmb = (unsigned short*)(ws + 52428800);      // M*512 bf16  26,214,400 B
  unsigned short* zb = (unsigned short*)(ws + 78643200);       // M*512 bf16  26,214,400 B
  unsigned short* xab = (unsigned short*)(ws + 104857600);     // M*512 bf16  26,214,400 B
  float* wfold = (float*)(ws + 131072000);                     // 2*128*512 f32  524,288 B
  // end: 131,596,288 B

  dim3 tb(32, 8);
  trans_in<<<dim3(50, 32, 2), tb, 0, stream>>>(x, xflat);
  // in-MLP: gelu(xflat@fc1^T+b) -> bufA ; bufA@fc2^T+b -> hbuf (f32)
  gemm_k<1, 0><<<dim3(2, 400), 256, 0, stream>>>(xflat, 128, fc1w, 128, fc1b, bufA, 128, 128, 0);
  gemm_k<4, 0><<<dim3(4, 400), 256, 0, stream>>>(bufA, 128, fc2w, 128, fc2b, hbuf, 256, 128, 0);

  for (int i = 0; i < 2; ++i) {
    const float* igw_i = igw + (size_t)i * 196608;
    const float* fgw_i = fgw + (size_t)i * 196608;
    fold_k<<<dim3(256), 256, 0, stream>>>(igw_i, fgw_i, qw + i * 2048, kw + i * 2048, wfold);
    ln_k<<<dim3(MTOK), 64, 0, stream>>>(hbuf, nw + i * 256, nb + i * 256, bufD, i);
    // up-proj split into xm / z halves
    gemm_k<0, 0><<<dim3(8, 400), 256, 0, stream>>>(bufD, 256, upw + (size_t)i * 262144, 256,
                                                   upb + i * 1024, xmb, 512, 256, 0);
    gemm_k<0, 0><<<dim3(8, 400), 256, 0, stream>>>(bufD, 256, upw + (size_t)i * 262144 + 131072,
                                                   256, upb + i * 1024 + 512, zb, 512, 256, 0);
    conv_k<<<dim3(NPOS), 512, 0, stream>>>(xmb, cw + i * 2048, cb + i * 512, xab);
    // gates: ig = xa@Wfold_ig^T + xm@igw_x^T + b ; fg likewise
    gemm_k<0, 0><<<dim3(2, 400), 256, 0, stream>>>(xab, 512, wfold, 512, igbias + i * 128,
                                                   bufA, 128, 512, 0);
    gemm_k<3, 0><<<dim3(2, 400), 256, 0, stream>>>(xmb, 512, igw_i + 1024, 1536,
                                                   (const float*)nullptr, bufA, 128, 512, 0);
    gemm_k<0, 0><<<dim3(2, 400), 256, 0, stream>>>(xab, 512, wfold + 65536, 512,
                                                   fgbias + i * 128, fgb, 128, 512, 0);
    gemm_k<3, 0><<<dim3(2, 400), 256, 0, stream>>>(xmb, 512, fgw_i + 1024, 1536,
                                                   (const float*)nullptr, fgb, 128, 512, 0);
    mlstm_k<<<dim3(NPOS), 128, 0, stream>>>(xab, xmb, zb, bufA, fgb, qw + i * 2048,
                                            kw + i * 2048, onw + i * 512, onb + i * 512,
                                            skp + i * 512);
    // down-proj, epilogue adds into hbuf at flip-mapped rows
    gemm_k<2, 0><<<dim3(4, 400), 256, 0, stream>>>(xab, 512, dww + (size_t)i * 131072, 512,
                                                   dwb + i * 256, hbuf, 256, 512, i);
  }

  // out-MLP
  gemm_k<1, 1><<<dim3(4, 400), 256, 0, stream>>>(hbuf, 256, ofc1w, 256, ofc1b, bufD, 256, 256, 0);
  gemm_k<0, 0><<<dim3(2, 400), 256, 0, stream>>>(bufD, 256, ofc2w, 256, ofc2b, bufA, 128, 256, 0);
  trans_out<<<dim3(50, 32, 2), tb, 0, stream>>>(x, bufA, out);
}

// Round 3
// 467.142 us; speedup vs baseline: 2.9131x; 2.9131x over previous
//
#include <hip/hip_runtime.h>
#include <cstddef>
#include <cstdint>

// B=2, NF=8(seq), DIM=128, HW=1600 -> Bp=3200 positions, M=25600 token rows
// HID=256, INNER=512, NH=128, DH=4

#define NPOS 3200
#define MTOK 25600

typedef __attribute__((ext_vector_type(8))) short short8;
typedef __attribute__((ext_vector_type(8))) unsigned short u16x8;
typedef __attribute__((ext_vector_type(4))) float f32x4;

__device__ __forceinline__ float bf2f(unsigned short u) {
  union { uint32_t i; float f; } v; v.i = ((uint32_t)u) << 16; return v.f;
}
__device__ __forceinline__ unsigned short f2bf(float f) {
  union { float f; uint32_t i; } v; v.f = f;
  uint32_t r = (v.i + 0x7fffu + ((v.i >> 16) & 1u)) >> 16;
  return (unsigned short)r;
}
__device__ __forceinline__ float geluf(float x) {
  return 0.5f * x * (1.0f + erff(x * 0.70710678118654752f));
}
__device__ __forceinline__ float siluf(float x) {
  return x / (1.0f + expf(-x));
}

// ---------- weight conversion helpers ----------
__global__ __launch_bounds__(256) void cvt_k(const float* __restrict__ src,
                                             unsigned short* __restrict__ dst, int n) {
  int i = blockIdx.x * 256 + threadIdx.x;
  if (i < n) dst[i] = f2bf(src[i]);
}

// gx slice: dst[r*512+c] = src[r*1536 + c], r<128, c<512
__global__ __launch_bounds__(256) void cvt_gx_k(const float* __restrict__ src,
                                                unsigned short* __restrict__ dst) {
  int i = blockIdx.x * 256 + threadIdx.x;  // 65536
  int r = i >> 9, c = i & 511;
  dst[i] = f2bf(src[(size_t)r * 1536 + c]);
}

// fold gate weights through q/k projections -> bf16 (256 x 512): rows 0-127 ig, 128-255 fg
__global__ __launch_bounds__(256) void fold_k(const float* __restrict__ igw,
                                              const float* __restrict__ fgw,
                                              const float* __restrict__ qw,
                                              const float* __restrict__ kw,
                                              unsigned short* __restrict__ wfold) {
  const int tid = blockIdx.x * 256 + threadIdx.x;  // 65536
  const int j = tid >> 9;
  const int c = tid & 511;
  const int n = c >> 2, d = c & 3;
  float si = 0.f, sf = 0.f;
#pragma unroll
  for (int e = 0; e < 4; ++e) {
    const float qv = qw[n * 16 + e * 4 + d];
    const float kv = kw[n * 16 + e * 4 + d];
    si += igw[j * 1536 + n * 4 + e] * qv + igw[j * 1536 + 512 + n * 4 + e] * kv;
    sf += fgw[j * 1536 + n * 4 + e] * qv + fgw[j * 1536 + 512 + n * 4 + e] * kv;
  }
  wfold[(size_t)j * 512 + c] = f2bf(si);
  wfold[65536 + (size_t)j * 512 + c] = f2bf(sf);
}

// ---------- transpose in: x (B,1024,1600) fp32 -> xflat (B*1600, 1024) bf16 ----------
__global__ __launch_bounds__(256) void trans_in(const float* __restrict__ x,
                                                unsigned short* __restrict__ xf) {
  __shared__ float tile[32][33];
  const int b = blockIdx.z;
  const int hw0 = blockIdx.x * 32;
  const int sc0 = blockIdx.y * 32;
  const int tx = threadIdx.x, ty = threadIdx.y;  // 32 x 8
#pragma unroll
  for (int i = 0; i < 32; i += 8)
    tile[ty + i][tx] = x[((size_t)b * 1024 + sc0 + ty + i) * 1600 + hw0 + tx];
  __syncthreads();
#pragma unroll
  for (int i = 0; i < 32; i += 8)
    xf[((size_t)b * 1600 + hw0 + ty + i) * 1024 + sc0 + tx] = f2bf(tile[tx][ty + i]);
}

// ---------- transpose out: out[b,sc,hw] = x[b,sc,hw] + o[(b*1600+hw)*128 + sc] ----------
__global__ __launch_bounds__(256) void trans_out(const float* __restrict__ x,
                                                 const unsigned short* __restrict__ o,
                                                 float* __restrict__ out) {
  __shared__ float tile[32][33];
  const int b = blockIdx.z;
  const int hw0 = blockIdx.x * 32;
  const int sc0 = blockIdx.y * 32;
  const int tx = threadIdx.x, ty = threadIdx.y;
#pragma unroll
  for (int i = 0; i < 32; i += 8)
    tile[ty + i][tx] = bf2f(o[((size_t)b * 1600 + hw0 + ty + i) * 1024 + sc0 + tx]);
  __syncthreads();
#pragma unroll
  for (int i = 0; i < 32; i += 8) {
    size_t idx = ((size_t)b * 1024 + sc0 + ty + i) * 1600 + hw0 + tx;
    out[idx] = x[idx] + tile[tx][ty + i];
  }
}

// ---------- MFMA bf16 GEMM: C = epilogue(A @ W^T) ----------
// A: bf16 (M x lda). W: bf16 (N x ldw). 128x128 tile, BK=32, 4 waves (2x2), 64x64/wave.
// MODE 0: C_bf16 = v + bias
// MODE 1: C_bf16 = gelu(v + bias)
// MODE 2: C_f32[flip-row] += v + bias
// MODE 3: C_bf16 += v
// MODE 4: C_f32 = v + bias
// MODE 5: C_bf16 = v
template <int MODE>
__global__ __launch_bounds__(256) void mgemm(const unsigned short* __restrict__ A, int lda,
                                             const unsigned short* __restrict__ W, int ldw,
                                             const float* __restrict__ bias,
                                             void* __restrict__ Cv, int ldc, int K,
                                             int flip) {
  __shared__ __align__(16) unsigned short Als[4][128][8];  // [kchunk][row][8] = 8 KB
  __shared__ __align__(16) unsigned short Bls[4][128][8];
  const int t = threadIdx.x;
  const int lane = t & 63, wid = t >> 6;
  const int wr = wid >> 1, wc = wid & 1;
  const int bm = blockIdx.y * 128, bn = blockIdx.x * 128;
  const int srow = t >> 1;            // 0..127
  const int skh = (t & 1) << 4;       // 0 or 16
  const int kc = lane >> 4;           // 0..3
  const int lr = lane & 15;
  f32x4 acc[4][4] = {};
  const unsigned short* Ap = A + (size_t)(bm + srow) * lda + skh;
  const unsigned short* Wp = W + (size_t)(bn + srow) * ldw + skh;
  for (int k0 = 0; k0 < K; k0 += 32) {
    u16x8 a0 = *(const u16x8*)(Ap + k0);
    u16x8 a1 = *(const u16x8*)(Ap + k0 + 8);
    u16x8 b0 = *(const u16x8*)(Wp + k0);
    u16x8 b1 = *(const u16x8*)(Wp + k0 + 8);
    __syncthreads();  // protect LDS from previous iteration's readers
    const int ch = skh >> 3;  // 0 or 2
    *(u16x8*)&Als[ch][srow][0] = a0;
    *(u16x8*)&Als[ch + 1][srow][0] = a1;
    *(u16x8*)&Bls[ch][srow][0] = b0;
    *(u16x8*)&Bls[ch + 1][srow][0] = b1;
    __syncthreads();
    short8 af[4], bf[4];
#pragma unroll
    for (int mi = 0; mi < 4; ++mi) af[mi] = *(const short8*)&Als[kc][wr * 64 + mi * 16 + lr][0];
#pragma unroll
    for (int ni = 0; ni < 4; ++ni) bf[ni] = *(const short8*)&Bls[kc][wc * 64 + ni * 16 + lr][0];
#pragma unroll
    for (int mi = 0; mi < 4; ++mi)
#pragma unroll
      for (int ni = 0; ni < 4; ++ni)
        acc[mi][ni] = __builtin_amdgcn_mfma_f32_16x16x32_bf16(af[mi], bf[ni], acc[mi][ni], 0, 0, 0);
  }
  // epilogue: row = bm + wr*64 + mi*16 + (lane>>4)*4 + j ; col = bn + wc*64 + ni*16 + lr
#pragma unroll
  for (int mi = 0; mi < 4; ++mi) {
#pragma unroll
    for (int j = 0; j < 4; ++j) {
      const int m = bm + wr * 64 + mi * 16 + (lane >> 4) * 4 + j;
#pragma unroll
      for (int ni = 0; ni < 4; ++ni) {
        const int col = bn + wc * 64 + ni * 16 + lr;
        float v = acc[mi][ni][j];
        if (MODE == 0 || MODE == 1 || MODE == 4) v += bias[col];
        if (MODE == 1) v = geluf(v);
        if (MODE == 0 || MODE == 1 || MODE == 5) {
          ((unsigned short*)Cv)[(size_t)m * ldc + col] = f2bf(v);
        } else if (MODE == 3) {
          unsigned short* p = (unsigned short*)Cv + (size_t)m * ldc + col;
          *p = f2bf(bf2f(*p) + v);
        } else if (MODE == 4) {
          ((float*)Cv)[(size_t)m * ldc + col] = v;
        } else {  // MODE 2
          const int pq = m >> 3, s = m & 7;
          const int fs = flip ? (7 - s) : s;
          float* p = (float*)Cv + (size_t)(pq * 8 + fs) * ldc + col;
          *p += v + bias[col];
        }
      }
    }
  }
}

// ---------- layernorm with flip-on-read: y bf16 ----------
__global__ __launch_bounds__(64) void ln_k(const float* __restrict__ h,
                                           const float* __restrict__ w,
                                           const float* __restrict__ b,
                                           unsigned short* __restrict__ y, int flip) {
  const int m = blockIdx.x;
  const int p = m >> 3, s = m & 7;
  const int ss = flip ? (7 - s) : s;
  const float* row = h + (size_t)(p * 8 + ss) * 256;
  const int lane = threadIdx.x;
  float4 v = *(const float4*)(row + lane * 4);
  float sum = v.x + v.y + v.z + v.w;
  float sq = v.x * v.x + v.y * v.y + v.z * v.z + v.w * v.w;
#pragma unroll
  for (int o = 32; o > 0; o >>= 1) {
    sum += __shfl_xor(sum, o);
    sq += __shfl_xor(sq, o);
  }
  float mu = sum * (1.f / 256.f);
  float var = sq * (1.f / 256.f) - mu * mu;
  float r = rsqrtf(var + 1e-5f);
  float4 wv = *(const float4*)(w + lane * 4);
  float4 bv = *(const float4*)(b + lane * 4);
  ushort4 o_;
  o_.x = f2bf((v.x - mu) * r * wv.x + bv.x);
  o_.y = f2bf((v.y - mu) * r * wv.y + bv.y);
  o_.z = f2bf((v.z - mu) * r * wv.z + bv.z);
  o_.w = f2bf((v.w - mu) * r * wv.w + bv.w);
  *(ushort4*)(y + (size_t)m * 256 + lane * 4) = o_;
}

// ---------- causal depthwise conv(4) + silu: xm bf16 -> xa bf16 ----------
__global__ __launch_bounds__(512) void conv_k(const unsigned short* __restrict__ xm,
                                              const float* __restrict__ cw,
                                              const float* __restrict__ cb,
                                              unsigned short* __restrict__ xa) {
  const int p = blockIdx.x;
  const int c = threadIdx.x;
  float v[8];
#pragma unroll
  for (int s = 0; s < 8; ++s) v[s] = bf2f(xm[(size_t)(p * 8 + s) * 512 + c]);
  const float4 cwv = *(const float4*)(cw + c * 4);
  const float cbv = cb[c];
#pragma unroll
  for (int s = 0; s < 8; ++s) {
    float acc = cbv + v[s] * cwv.w;
    if (s >= 1) acc += v[s - 1] * cwv.z;
    if (s >= 2) acc += v[s - 2] * cwv.y;
    if (s >= 3) acc += v[s - 3] * cwv.x;
    xa[(size_t)(p * 8 + s) * 512 + c] = f2bf(siluf(acc));
  }
}

// ---------- mLSTM (q/k proj fused) + head-LN + skip + z-gate ----------
__global__ __launch_bounds__(128) void mlstm_k(unsigned short* __restrict__ xab,
                                               const unsigned short* __restrict__ xmb,
                                               const unsigned short* __restrict__ zb,
                                               const unsigned short* __restrict__ gateb,
                                               const float* __restrict__ igbias,
                                               const float* __restrict__ fgbias,
                                               const float* __restrict__ qw,
                                               const float* __restrict__ kw,
                                               const float* __restrict__ onw,
                                               const float* __restrict__ onb,
                                               const float* __restrict__ skp) {
  const int p = blockIdx.x;
  const int n = threadIdx.x;
  float qwv[4][4], kwv[4][4];
#pragma unroll
  for (int e = 0; e < 4; ++e) {
    float4 q4 = *(const float4*)(qw + n * 16 + e * 4);
    float4 k4 = *(const float4*)(kw + n * 16 + e * 4);
    qwv[e][0] = q4.x; qwv[e][1] = q4.y; qwv[e][2] = q4.z; qwv[e][3] = q4.w;
    kwv[e][0] = k4.x; kwv[e][1] = k4.y; kwv[e][2] = k4.z; kwv[e][3] = k4.w;
  }
  const float igb_n = igbias[n], fgb_n = fgbias[n];
  float xa[8][4], q[8][4], k[8][4], v[8][4], lfc[8], ig[8];
  float run = 0.f;
#pragma unroll
  for (int s = 0; s < 8; ++s) {
    const size_t row = (size_t)(p * 8 + s);
    ushort4 xa4 = *(const ushort4*)(xab + row * 512 + n * 4);
    xa[s][0] = bf2f(xa4.x); xa[s][1] = bf2f(xa4.y); xa[s][2] = bf2f(xa4.z); xa[s][3] = bf2f(xa4.w);
    ushort4 v4 = *(const ushort4*)(xmb + row * 512 + n * 4);
    v[s][0] = bf2f(v4.x); v[s][1] = bf2f(v4.y); v[s][2] = bf2f(v4.z); v[s][3] = bf2f(v4.w);
#pragma unroll
    for (int e = 0; e < 4; ++e) {
      q[s][e] = xa[s][0] * qwv[e][0] + xa[s][1] * qwv[e][1] + xa[s][2] * qwv[e][2] + xa[s][3] * qwv[e][3];
      k[s][e] = xa[s][0] * kwv[e][0] + xa[s][1] * kwv[e][1] + xa[s][2] * kwv[e][2] + xa[s][3] * kwv[e][3];
    }
    ig[s] = bf2f(gateb[row * 256 + n]) + igb_n;
    const float f = bf2f(gateb[row * 256 + 128 + n]) + fgb_n;
    const float ls = (f > 0.f) ? -log1pf(expf(-f)) : (f - log1pf(expf(f)));
    run += ls;
    lfc[s] = run;
  }
  const float4 onwv = *(const float4*)(onw + n * 4);
  const float4 onbv = *(const float4*)(onb + n * 4);
  const float4 skv = *(const float4*)(skp + n * 4);
#pragma unroll
  for (int s = 0; s < 8; ++s) {
    float crow[8];
    float mx = -1e30f;
#pragma unroll
    for (int t = 0; t < 8; ++t)
      if (t <= s) {
        const float ld = lfc[s] - lfc[t] + ig[t];
        crow[t] = ld;
        mx = fmaxf(mx, ld);
      }
    float csum = 0.f;
#pragma unroll
    for (int t = 0; t < 8; ++t)
      if (t <= s) {
        const float dm = expf(crow[t] - mx);
        const float qkd = (q[s][0] * k[t][0] + q[s][1] * k[t][1] + q[s][2] * k[t][2] + q[s][3] * k[t][3]) * 0.5f;
        crow[t] = qkd * dm;
        csum += crow[t];
      }
    const float inv = 1.f / (fmaxf(fabsf(csum), expf(-mx)) + 1e-6f);
    float o0 = 0, o1 = 0, o2 = 0, o3 = 0;
#pragma unroll
    for (int t = 0; t < 8; ++t)
      if (t <= s) {
        const float cn = crow[t];
        o0 += cn * v[t][0]; o1 += cn * v[t][1]; o2 += cn * v[t][2]; o3 += cn * v[t][3];
      }
    o0 *= inv; o1 *= inv; o2 *= inv; o3 *= inv;
    const float mu = 0.25f * (o0 + o1 + o2 + o3);
    const float d0 = o0 - mu, d1 = o1 - mu, d2 = o2 - mu, d3 = o3 - mu;
    const float var = 0.25f * (d0 * d0 + d1 * d1 + d2 * d2 + d3 * d3);
    const float r = rsqrtf(var + 1e-5f);
    const size_t row = (size_t)(p * 8 + s);
    ushort4 z4 = *(const ushort4*)(zb + row * 512 + n * 4);
    ushort4 ge;
    ge.x = f2bf((d0 * r * onwv.x + onbv.x + skv.x * xa[s][0]) * siluf(bf2f(z4.x)));
    ge.y = f2bf((d1 * r * onwv.y + onbv.y + skv.y * xa[s][1]) * siluf(bf2f(z4.y)));
    ge.z = f2bf((d2 * r * onwv.z + onbv.z + skv.z * xa[s][2]) * siluf(bf2f(z4.z)));
    ge.w = f2bf((d3 * r * onwv.w + onbv.w + skv.w * xa[s][3]) * siluf(bf2f(z4.w)));
    *(ushort4*)(xab + row * 512 + n * 4) = ge;
  }
}

extern "C" void kernel_launch(void* const* d_in, const int* in_sizes, int n_in,
                              void* d_out, int out_size, void* d_ws, size_t ws_size,
                              hipStream_t stream) {
  const float* x = (const float*)d_in[0];
  const float* fc1w = (const float*)d_in[1];
  const float* fc1b = (const float*)d_in[2];
  const float* fc2w = (const float*)d_in[3];
  const float* fc2b = (const float*)d_in[4];
  const float* ofc1w = (const float*)d_in[5];
  const float* ofc1b = (const float*)d_in[6];
  const float* ofc2w = (const float*)d_in[7];
  const float* ofc2b = (const float*)d_in[8];
  const float* nw = (const float*)d_in[9];
  const float* nb = (const float*)d_in[10];
  const float* upw = (const float*)d_in[11];
  const float* upb = (const float*)d_in[12];
  const float* cw = (const float*)d_in[13];
  const float* cb = (const float*)d_in[14];
  const float* qw = (const float*)d_in[15];
  const float* kw = (const float*)d_in[16];
  const float* igw = (const float*)d_in[17];
  const float* igbias = (const float*)d_in[18];
  const float* fgw = (const float*)d_in[19];
  const float* fgbias = (const float*)d_in[20];
  const float* onw = (const float*)d_in[21];
  const float* onb = (const float*)d_in[22];
  const float* skp = (const float*)d_in[23];
  const float* dww = (const float*)d_in[24];
  const float* dwb = (const float*)d_in[25];
  float* out = (float*)d_out;

  // workspace layout (byte offsets), ~127 MB total
  char* ws = (char*)d_ws;
  float* hbuf = (float*)ws;                                   // M*256 f32  26,214,400 B
  unsigned short* bufD = (unsigned short*)(ws + 26214400);    // M*256 bf16 13,107,200 B
  unsigned short* gateb = bufD;                               // alias: disjoint lifetime
  unsigned short* bufA = (unsigned short*)(ws + 39321600);    // M*128 bf16  6,553,600 B
  unsigned short* xmb = (unsigned short*)(ws + 45875200);     // M*512 bf16 26,214,400 B
  unsigned short* zb = (unsigned short*)(ws + 72089600);      // M*512 bf16 26,214,400 B
  unsigned short* xab = (unsigned short*)(ws + 98304000);     // M*512 bf16 26,214,400 B
  unsigned short* xflat = xab;                                // alias: dead before conv
  unsigned short* wb = (unsigned short*)(ws + 124518400);     // bf16 weights ~2.4 MB
  unsigned short* fc1_16 = wb;            // 16384
  unsigned short* fc2_16 = wb + 16384;    // 32768
  unsigned short* ofc1_16 = wb + 49152;   // 65536
  unsigned short* ofc2_16 = wb + 114688;  // 32768
  unsigned short* up_16 = wb + 147456;    // 524288 (2 layers)
  unsigned short* dw_16 = wb + 671744;    // 262144 (2 layers)
  unsigned short* wfold_16 = wb + 933888; // 131072 (per-layer)
  unsigned short* gx_16 = wb + 1064960;   // 131072 (per-layer)

  // weight conversions
  cvt_k<<<dim3(64), 256, 0, stream>>>(fc1w, fc1_16, 16384);
  cvt_k<<<dim3(128), 256, 0, stream>>>(fc2w, fc2_16, 32768);
  cvt_k<<<dim3(256), 256, 0, stream>>>(ofc1w, ofc1_16, 65536);
  cvt_k<<<dim3(128), 256, 0, stream>>>(ofc2w, ofc2_16, 32768);
  cvt_k<<<dim3(2048), 256, 0, stream>>>(upw, up_16, 524288);
  cvt_k<<<dim3(1024), 256, 0, stream>>>(dww, dw_16, 262144);

  dim3 tb(32, 8);
  trans_in<<<dim3(50, 32, 2), tb, 0, stream>>>(x, xflat);
  // in-MLP
  mgemm<1><<<dim3(1, 200), 256, 0, stream>>>(xflat, 128, fc1_16, 128, fc1b, bufA, 128, 128, 0);
  mgemm<4><<<dim3(2, 200), 256, 0, stream>>>(bufA, 128, fc2_16, 128, fc2b, hbuf, 256, 128, 0);

  for (int i = 0; i < 2; ++i) {
    const float* igw_i = igw + (size_t)i * 196608;
    const float* fgw_i = fgw + (size_t)i * 196608;
    fold_k<<<dim3(256), 256, 0, stream>>>(igw_i, fgw_i, qw + i * 2048, kw + i * 2048, wfold_16);
    cvt_gx_k<<<dim3(256), 256, 0, stream>>>(igw_i + 1024, gx_16);
    cvt_gx_k<<<dim3(256), 256, 0, stream>>>(fgw_i + 1024, gx_16 + 65536);
    ln_k<<<dim3(MTOK), 64, 0, stream>>>(hbuf, nw + i * 256, nb + i * 256, bufD, i);
    // up-proj halves (xm, z)
    mgemm<0><<<dim3(4, 200), 256, 0, stream>>>(bufD, 256, up_16 + (size_t)i * 262144, 256,
                                               upb + i * 1024, xmb, 512, 256, 0);
    mgemm<0><<<dim3(4, 200), 256, 0, stream>>>(bufD, 256, up_16 + (size_t)i * 262144 + 131072,
                                               256, upb + i * 1024 + 512, zb, 512, 256, 0);
    conv_k<<<dim3(NPOS), 512, 0, stream>>>(xmb, cw + i * 2048, cb + i * 512, xab);
    // gates (ig|fg combined, N=256): xa @ wfold^T then += xm @ gx^T
    mgemm<5><<<dim3(2, 200), 256, 0, stream>>>(xab, 512, wfold_16, 512,
                                               (const float*)nullptr, gateb, 256, 512, 0);
    mgemm<3><<<dim3(2, 200), 256, 0, stream>>>(xmb, 512, gx_16, 512,
                                               (const float*)nullptr, gateb, 256, 512, 0);
    mlstm_k<<<dim3(NPOS), 128, 0, stream>>>(xab, xmb, zb, gateb, igbias + i * 128,
                                            fgbias + i * 128, qw + i * 2048, kw + i * 2048,
                                            onw + i * 512, onb + i * 512, skp + i * 512);
    // down-proj with flip-add into hbuf
    mgemm<2><<<dim3(2, 200), 256, 0, stream>>>(xab, 512, dw_16 + (size_t)i * 131072, 512,
                                               dwb + i * 256, hbuf, 256, 512, i);
  }

  // out-MLP: hbuf -> bf16 (reuse xmb), then two GEMMs
  cvt_k<<<dim3(25600), 256, 0, stream>>>(hbuf, xmb, 6553600);
  mgemm<1><<<dim3(2, 200), 256, 0, stream>>>(xmb, 256, ofc1_16, 256, ofc1b, bufD, 256, 256, 0);
  mgemm<0><<<dim3(1, 200), 256, 0, stream>>>(bufD, 256, ofc2_16, 256, ofc2b, bufA, 128, 256, 0);
  trans_out<<<dim3(50, 32, 2), tb, 0, stream>>>(x, bufA, out);
}

// Round 4
// 353.865 us; speedup vs baseline: 3.8456x; 1.3201x over previous
//
#include <hip/hip_runtime.h>
#include <cstddef>
#include <cstdint>

// B=2, NF=8(seq), DIM=128, HW=1600 -> Bp=3200 positions, M=25600 token rows
// HID=256, INNER=512, NH=128, DH=4

#define NPOS 3200
#define MTOK 25600

typedef __attribute__((ext_vector_type(8))) short short8;
typedef __attribute__((ext_vector_type(8))) unsigned short u16x8;
typedef __attribute__((ext_vector_type(4))) float f32x4;

__device__ __forceinline__ float bf2f(unsigned short u) {
  union { uint32_t i; float f; } v; v.i = ((uint32_t)u) << 16; return v.f;
}
__device__ __forceinline__ unsigned short f2bf(float f) {
  union { float f; uint32_t i; } v; v.f = f;
  uint32_t r = (v.i + 0x7fffu + ((v.i >> 16) & 1u)) >> 16;
  return (unsigned short)r;
}
__device__ __forceinline__ float geluf(float x) {
  return 0.5f * x * (1.0f + erff(x * 0.70710678118654752f));
}
__device__ __forceinline__ float fast_rcp(float x) { return __builtin_amdgcn_rcpf(x); }
__device__ __forceinline__ float silu_fast(float x) {
  return x * fast_rcp(1.0f + __expf(-x));
}

// bf16 weight-buffer offsets (elements)
#define OFF_FC1 0
#define OFF_FC2 16384
#define OFF_OFC1 49152
#define OFF_OFC2 114688
#define OFF_UP 147456
#define OFF_DW 671744
#define OFF_GW 933888
#define WB_ELEMS 1458176

// ---------- merged weight prep: cvt all weights, build gate weight [fold|gx], gate bias ----------
__global__ __launch_bounds__(256) void wprep(const float* __restrict__ fc1w,
                                             const float* __restrict__ fc2w,
                                             const float* __restrict__ ofc1w,
                                             const float* __restrict__ ofc2w,
                                             const float* __restrict__ upw,
                                             const float* __restrict__ dww,
                                             const float* __restrict__ igw,
                                             const float* __restrict__ fgw,
                                             const float* __restrict__ qw,
                                             const float* __restrict__ kw,
                                             const float* __restrict__ igbias,
                                             const float* __restrict__ fgbias,
                                             unsigned short* __restrict__ wb,
                                             float* __restrict__ gbias) {
  int i = blockIdx.x * 256 + threadIdx.x;
  if (i < 16384) { wb[OFF_FC1 + i] = f2bf(fc1w[i]); return; }
  i -= 16384;
  if (i < 32768) { wb[OFF_FC2 + i] = f2bf(fc2w[i]); return; }
  i -= 32768;
  if (i < 65536) { wb[OFF_OFC1 + i] = f2bf(ofc1w[i]); return; }
  i -= 65536;
  if (i < 32768) { wb[OFF_OFC2 + i] = f2bf(ofc2w[i]); return; }
  i -= 32768;
  if (i < 524288) { wb[OFF_UP + i] = f2bf(upw[i]); return; }
  i -= 524288;
  if (i < 262144) { wb[OFF_DW + i] = f2bf(dww[i]); return; }
  i -= 262144;
  if (i < 262144) {  // gx part of gate weight: W[row, 512 + c]
    const int l = i >> 17;
    const int r = i & 131071;
    const int gate = r >> 16;
    const int rr = r & 65535;
    const int row = rr >> 9, c = rr & 511;
    const float* src = (gate ? fgw : igw) + (size_t)l * 196608 + (size_t)row * 1536 + 1024 + c;
    wb[OFF_GW + (size_t)l * 262144 + (size_t)(gate * 128 + row) * 1024 + 512 + c] = f2bf(*src);
    return;
  }
  i -= 262144;
  if (i < 131072) {  // fold part of gate weight: W[row, c], c<512
    const int l = i >> 16;
    const int r = i & 65535;
    const int jj = r >> 9, c = r & 511;
    const int n = c >> 2, d = c & 3;
    const float* igp = igw + (size_t)l * 196608;
    const float* fgp = fgw + (size_t)l * 196608;
    const float* qp = qw + l * 2048;
    const float* kp = kw + l * 2048;
    float si = 0.f, sf = 0.f;
#pragma unroll
    for (int e = 0; e < 4; ++e) {
      const float qv = qp[n * 16 + e * 4 + d];
      const float kv = kp[n * 16 + e * 4 + d];
      si += igp[jj * 1536 + n * 4 + e] * qv + igp[jj * 1536 + 512 + n * 4 + e] * kv;
      sf += fgp[jj * 1536 + n * 4 + e] * qv + fgp[jj * 1536 + 512 + n * 4 + e] * kv;
    }
    wb[OFF_GW + (size_t)l * 262144 + (size_t)jj * 1024 + c] = f2bf(si);
    wb[OFF_GW + (size_t)l * 262144 + (size_t)(128 + jj) * 1024 + c] = f2bf(sf);
    return;
  }
  i -= 131072;
  if (i < 512) {
    const int l = i >> 8, c = i & 255;
    gbias[l * 256 + c] = (c < 128) ? igbias[l * 128 + c] : fgbias[l * 128 + c - 128];
  }
}

// ---------- transpose in: x (B,1024,1600) fp32 -> xflat (B*1600, 1024) bf16 ----------
__global__ __launch_bounds__(256) void trans_in(const float* __restrict__ x,
                                                unsigned short* __restrict__ xf) {
  __shared__ float tile[32][33];
  const int b = blockIdx.z;
  const int hw0 = blockIdx.x * 32;
  const int sc0 = blockIdx.y * 32;
  const int tx = threadIdx.x, ty = threadIdx.y;  // 32 x 8
#pragma unroll
  for (int i = 0; i < 32; i += 8)
    tile[ty + i][tx] = x[((size_t)b * 1024 + sc0 + ty + i) * 1600 + hw0 + tx];
  __syncthreads();
#pragma unroll
  for (int i = 0; i < 32; i += 8)
    xf[((size_t)b * 1600 + hw0 + ty + i) * 1024 + sc0 + tx] = f2bf(tile[tx][ty + i]);
}

// ---------- transpose out: out[b,sc,hw] = x[b,sc,hw] + o[(b*1600+hw)*1024 + sc] ----------
__global__ __launch_bounds__(256) void trans_out(const float* __restrict__ x,
                                                 const unsigned short* __restrict__ o,
                                                 float* __restrict__ out) {
  __shared__ float tile[32][33];
  const int b = blockIdx.z;
  const int hw0 = blockIdx.x * 32;
  const int sc0 = blockIdx.y * 32;
  const int tx = threadIdx.x, ty = threadIdx.y;
#pragma unroll
  for (int i = 0; i < 32; i += 8)
    tile[ty + i][tx] = bf2f(o[((size_t)b * 1600 + hw0 + ty + i) * 1024 + sc0 + tx]);
  __syncthreads();
#pragma unroll
  for (int i = 0; i < 32; i += 8) {
    size_t idx = ((size_t)b * 1024 + sc0 + ty + i) * 1600 + hw0 + tx;
    out[idx] = x[idx] + tile[tx][ty + i];
  }
}

// ---------- MFMA bf16 GEMM: C = epilogue(A @ W^T) ----------
// A split over K: cols [0,KA) from A (lda), [KA,K) from A2 (lda2). W: bf16 (N x ldw).
// 128x128 tile, BK=32, 4 waves, 64x64/wave.
// MODE 0: C_bf16 = v + bias
// MODE 1: C_bf16 = gelu(v + bias)
// MODE 2: C_f32[flip-row] += v + bias
// MODE 4: C_f32 = v + bias
// MODE 6: C_bf16[flip-row] = Cin_f32[flip-row] + v + bias
template <int MODE>
__global__ __launch_bounds__(256) void mgemm(const unsigned short* __restrict__ A, int lda,
                                             const unsigned short* __restrict__ A2, int lda2,
                                             int KA,
                                             const unsigned short* __restrict__ W, int ldw,
                                             const float* __restrict__ bias,
                                             const float* __restrict__ Cin,
                                             void* __restrict__ Cv, int ldc, int K,
                                             int flip) {
  __shared__ __align__(16) unsigned short Als[4][128][8];  // [kchunk][row][8]
  __shared__ __align__(16) unsigned short Bls[4][128][8];
  const int t = threadIdx.x;
  const int lane = t & 63, wid = t >> 6;
  const int wr = wid >> 1, wc = wid & 1;
  const int bm = blockIdx.y * 128, bn = blockIdx.x * 128;
  const int srow = t >> 1;       // 0..127
  const int skh = (t & 1) << 4;  // 0 or 16
  const int kc = lane >> 4;      // 0..3
  const int lr = lane & 15;
  f32x4 acc[4][4] = {};
  const unsigned short* ApA = A + (size_t)(bm + srow) * lda + skh;
  const unsigned short* ApB = A2 + (size_t)(bm + srow) * lda2 + skh;
  const unsigned short* Wp = W + (size_t)(bn + srow) * ldw + skh;
  for (int k0 = 0; k0 < K; k0 += 32) {
    const unsigned short* s_ = (k0 < KA) ? (ApA + k0) : (ApB + (k0 - KA));
    u16x8 a0 = *(const u16x8*)s_;
    u16x8 a1 = *(const u16x8*)(s_ + 8);
    u16x8 b0 = *(const u16x8*)(Wp + k0);
    u16x8 b1 = *(const u16x8*)(Wp + k0 + 8);
    __syncthreads();
    const int ch = skh >> 3;  // 0 or 2
    *(u16x8*)&Als[ch][srow][0] = a0;
    *(u16x8*)&Als[ch + 1][srow][0] = a1;
    *(u16x8*)&Bls[ch][srow][0] = b0;
    *(u16x8*)&Bls[ch + 1][srow][0] = b1;
    __syncthreads();
    short8 af[4], bf[4];
#pragma unroll
    for (int mi = 0; mi < 4; ++mi) af[mi] = *(const short8*)&Als[kc][wr * 64 + mi * 16 + lr][0];
#pragma unroll
    for (int ni = 0; ni < 4; ++ni) bf[ni] = *(const short8*)&Bls[kc][wc * 64 + ni * 16 + lr][0];
#pragma unroll
    for (int mi = 0; mi < 4; ++mi)
#pragma unroll
      for (int ni = 0; ni < 4; ++ni)
        acc[mi][ni] = __builtin_amdgcn_mfma_f32_16x16x32_bf16(af[mi], bf[ni], acc[mi][ni], 0, 0, 0);
  }
#pragma unroll
  for (int mi = 0; mi < 4; ++mi) {
#pragma unroll
    for (int j = 0; j < 4; ++j) {
      const int m = bm + wr * 64 + mi * 16 + (lane >> 4) * 4 + j;
#pragma unroll
      for (int ni = 0; ni < 4; ++ni) {
        const int col = bn + wc * 64 + ni * 16 + lr;
        float v = acc[mi][ni][j] + bias[col];
        if (MODE == 1) v = geluf(v);
        if (MODE == 0 || MODE == 1) {
          ((unsigned short*)Cv)[(size_t)m * ldc + col] = f2bf(v);
        } else if (MODE == 4) {
          ((float*)Cv)[(size_t)m * ldc + col] = v;
        } else if (MODE == 2) {
          const int pq = m >> 3, s = m & 7;
          const int fs = flip ? (7 - s) : s;
          ((float*)Cv)[(size_t)(pq * 8 + fs) * ldc + col] += v;
        } else {  // MODE 6
          const int pq = m >> 3, s = m & 7;
          const int fs = flip ? (7 - s) : s;
          const size_t idx = (size_t)(pq * 8 + fs) * ldc + col;
          ((unsigned short*)Cv)[idx] = f2bf(Cin[idx] + v);
        }
      }
    }
  }
}

// ---------- layernorm with flip-on-read: y bf16 (4 rows per 256-thread block) ----------
__global__ __launch_bounds__(256) void ln_k(const float* __restrict__ h,
                                            const float* __restrict__ w,
                                            const float* __restrict__ b,
                                            unsigned short* __restrict__ y, int flip) {
  const int m = blockIdx.x * 4 + (threadIdx.x >> 6);
  const int lane = threadIdx.x & 63;
  const int p = m >> 3, s = m & 7;
  const int ss = flip ? (7 - s) : s;
  const float* row = h + (size_t)(p * 8 + ss) * 256;
  float4 v = *(const float4*)(row + lane * 4);
  float sum = v.x + v.y + v.z + v.w;
  float sq = v.x * v.x + v.y * v.y + v.z * v.z + v.w * v.w;
#pragma unroll
  for (int o = 32; o > 0; o >>= 1) {
    sum += __shfl_xor(sum, o);
    sq += __shfl_xor(sq, o);
  }
  float mu = sum * (1.f / 256.f);
  float var = sq * (1.f / 256.f) - mu * mu;
  float r = rsqrtf(var + 1e-5f);
  float4 wv = *(const float4*)(w + lane * 4);
  float4 bv = *(const float4*)(b + lane * 4);
  ushort4 o_;
  o_.x = f2bf((v.x - mu) * r * wv.x + bv.x);
  o_.y = f2bf((v.y - mu) * r * wv.y + bv.y);
  o_.z = f2bf((v.z - mu) * r * wv.z + bv.z);
  o_.w = f2bf((v.w - mu) * r * wv.w + bv.w);
  *(ushort4*)(y + (size_t)m * 256 + lane * 4) = o_;
}

// ---------- causal depthwise conv(4) + silu: xz(xm half) -> xa bf16 ----------
__global__ __launch_bounds__(512) void conv_k(const unsigned short* __restrict__ xz,
                                              const float* __restrict__ cw,
                                              const float* __restrict__ cb,
                                              unsigned short* __restrict__ xa) {
  const int p = blockIdx.x;
  const int c = threadIdx.x;
  float v[8];
#pragma unroll
  for (int s = 0; s < 8; ++s) v[s] = bf2f(xz[(size_t)(p * 8 + s) * 1024 + c]);
  const float4 cwv = *(const float4*)(cw + c * 4);
  const float cbv = cb[c];
#pragma unroll
  for (int s = 0; s < 8; ++s) {
    float acc = cbv + v[s] * cwv.w;
    if (s >= 1) acc += v[s - 1] * cwv.z;
    if (s >= 2) acc += v[s - 2] * cwv.y;
    if (s >= 3) acc += v[s - 3] * cwv.x;
    xa[(size_t)(p * 8 + s) * 512 + c] = f2bf(silu_fast(acc));
  }
}

// ---------- mLSTM (q/k proj fused, fast-math) + head-LN + skip + z-gate ----------
__global__ __launch_bounds__(128) void mlstm_k(unsigned short* __restrict__ xab,
                                               const unsigned short* __restrict__ xz,
                                               const unsigned short* __restrict__ gateb,
                                               const float* __restrict__ qw,
                                               const float* __restrict__ kw,
                                               const float* __restrict__ onw,
                                               const float* __restrict__ onb,
                                               const float* __restrict__ skp) {
  const int p = blockIdx.x;
  const int n = threadIdx.x;
  float qwv[4][4], kwv[4][4];
#pragma unroll
  for (int e = 0; e < 4; ++e) {
    float4 q4 = *(const float4*)(qw + n * 16 + e * 4);
    float4 k4 = *(const float4*)(kw + n * 16 + e * 4);
    qwv[e][0] = q4.x; qwv[e][1] = q4.y; qwv[e][2] = q4.z; qwv[e][3] = q4.w;
    kwv[e][0] = k4.x; kwv[e][1] = k4.y; kwv[e][2] = k4.z; kwv[e][3] = k4.w;
  }
  float xa[8][4], k[8][4], v[8][4], lfc[8], ig[8];
  float run = 0.f;
#pragma unroll
  for (int s = 0; s < 8; ++s) {
    const size_t row = (size_t)(p * 8 + s);
    ushort4 xa4 = *(const ushort4*)(xab + row * 512 + n * 4);
    xa[s][0] = bf2f(xa4.x); xa[s][1] = bf2f(xa4.y); xa[s][2] = bf2f(xa4.z); xa[s][3] = bf2f(xa4.w);
    ushort4 v4 = *(const ushort4*)(xz + row * 1024 + n * 4);
    v[s][0] = bf2f(v4.x); v[s][1] = bf2f(v4.y); v[s][2] = bf2f(v4.z); v[s][3] = bf2f(v4.w);
#pragma unroll
    for (int e = 0; e < 4; ++e)
      k[s][e] = xa[s][0] * kwv[e][0] + xa[s][1] * kwv[e][1] + xa[s][2] * kwv[e][2] + xa[s][3] * kwv[e][3];
    ig[s] = bf2f(gateb[row * 256 + n]);
    const float f = bf2f(gateb[row * 256 + 128 + n]);
    // log_sigmoid(f) = min(f,0) - log(1 + exp(-|f|))
    const float ls = fminf(f, 0.f) - __logf(1.0f + __expf(-fabsf(f)));
    run += ls;
    lfc[s] = run;
  }
  const float4 onwv = *(const float4*)(onw + n * 4);
  const float4 onbv = *(const float4*)(onb + n * 4);
  const float4 skv = *(const float4*)(skp + n * 4);
#pragma unroll
  for (int s = 0; s < 8; ++s) {
    float q0 = 0, q1 = 0, q2 = 0, q3 = 0;
    q0 = xa[s][0] * qwv[0][0] + xa[s][1] * qwv[0][1] + xa[s][2] * qwv[0][2] + xa[s][3] * qwv[0][3];
    q1 = xa[s][0] * qwv[1][0] + xa[s][1] * qwv[1][1] + xa[s][2] * qwv[1][2] + xa[s][3] * qwv[1][3];
    q2 = xa[s][0] * qwv[2][0] + xa[s][1] * qwv[2][1] + xa[s][2] * qwv[2][2] + xa[s][3] * qwv[2][3];
    q3 = xa[s][0] * qwv[3][0] + xa[s][1] * qwv[3][1] + xa[s][2] * qwv[3][2] + xa[s][3] * qwv[3][3];
    float mx = -1e30f;
#pragma unroll
    for (int t = 0; t < 8; ++t)
      if (t <= s) mx = fmaxf(mx, lfc[s] - lfc[t] + ig[t]);
    float csum = 0.f;
    float o0 = 0, o1 = 0, o2 = 0, o3 = 0;
#pragma unroll
    for (int t = 0; t < 8; ++t)
      if (t <= s) {
        const float dm = __expf(lfc[s] - lfc[t] + ig[t] - mx);
        const float qkd = (q0 * k[t][0] + q1 * k[t][1] + q2 * k[t][2] + q3 * k[t][3]) * 0.5f;
        const float cc = qkd * dm;
        csum += cc;
        o0 += cc * v[t][0]; o1 += cc * v[t][1]; o2 += cc * v[t][2]; o3 += cc * v[t][3];
      }
    const float inv = fast_rcp(fmaxf(fabsf(csum), __expf(-mx)) + 1e-6f);
    o0 *= inv; o1 *= inv; o2 *= inv; o3 *= inv;
    const float mu = 0.25f * (o0 + o1 + o2 + o3);
    const float d0 = o0 - mu, d1 = o1 - mu, d2 = o2 - mu, d3 = o3 - mu;
    const float var = 0.25f * (d0 * d0 + d1 * d1 + d2 * d2 + d3 * d3);
    const float r = __builtin_amdgcn_rsqf(var + 1e-5f);
    const size_t row = (size_t)(p * 8 + s);
    ushort4 z4 = *(const ushort4*)(xz + row * 1024 + 512 + n * 4);
    ushort4 ge;
    ge.x = f2bf((d0 * r * onwv.x + onbv.x + skv.x * xa[s][0]) * silu_fast(bf2f(z4.x)));
    ge.y = f2bf((d1 * r * onwv.y + onbv.y + skv.y * xa[s][1]) * silu_fast(bf2f(z4.y)));
    ge.z = f2bf((d2 * r * onwv.z + onbv.z + skv.z * xa[s][2]) * silu_fast(bf2f(z4.z)));
    ge.w = f2bf((d3 * r * onwv.w + onbv.w + skv.w * xa[s][3]) * silu_fast(bf2f(z4.w)));
    *(ushort4*)(xab + row * 512 + n * 4) = ge;
  }
}

extern "C" void kernel_launch(void* const* d_in, const int* in_sizes, int n_in,
                              void* d_out, int out_size, void* d_ws, size_t ws_size,
                              hipStream_t stream) {
  const float* x = (const float*)d_in[0];
  const float* fc1w = (const float*)d_in[1];
  const float* fc1b = (const float*)d_in[2];
  const float* fc2w = (const float*)d_in[3];
  const float* fc2b = (const float*)d_in[4];
  const float* ofc1w = (const float*)d_in[5];
  const float* ofc1b = (const float*)d_in[6];
  const float* ofc2w = (const float*)d_in[7];
  const float* ofc2b = (const float*)d_in[8];
  const float* nw = (const float*)d_in[9];
  const float* nb = (const float*)d_in[10];
  const float* upw = (const float*)d_in[11];
  const float* upb = (const float*)d_in[12];
  const float* cw = (const float*)d_in[13];
  const float* cb = (const float*)d_in[14];
  const float* qw = (const float*)d_in[15];
  const float* kw = (const float*)d_in[16];
  const float* igw = (const float*)d_in[17];
  const float* igbias = (const float*)d_in[18];
  const float* fgw = (const float*)d_in[19];
  const float* fgbias = (const float*)d_in[20];
  const float* onw = (const float*)d_in[21];
  const float* onb = (const float*)d_in[22];
  const float* skp = (const float*)d_in[23];
  const float* dww = (const float*)d_in[24];
  const float* dwb = (const float*)d_in[25];
  float* out = (float*)d_out;

  // workspace layout (byte offsets), ~127.4 MB total
  char* ws = (char*)d_ws;
  float* hbuf = (float*)ws;                                 // M*256 f32   26,214,400
  unsigned short* bufD = (unsigned short*)(ws + 26214400);  // M*256 bf16  13,107,200 (ln-out/gateb/mid)
  unsigned short* bufA = (unsigned short*)(ws + 39321600);  // M*128 bf16   6,553,600
  unsigned short* xz = (unsigned short*)(ws + 45875200);    // M*1024 bf16 52,428,800 (xm|z; later hmirror)
  unsigned short* hmirror = xz;                             // M*256 bf16 (after mlstm layer 1)
  unsigned short* xab = (unsigned short*)(ws + 98304000);   // M*512 bf16  26,214,400
  unsigned short* xflat = xab;                              // alias: dead before conv
  unsigned short* wb = (unsigned short*)(ws + 124518400);   // WB_ELEMS bf16 = 2,916,352
  float* gbias = (float*)(ws + 124518400 + 2916352);        // 512 f32 = 2,048
  // end: 127,436,800

  wprep<<<dim3(5186), 256, 0, stream>>>(fc1w, fc2w, ofc1w, ofc2w, upw, dww, igw, fgw, qw, kw,
                                        igbias, fgbias, wb, gbias);

  dim3 tb(32, 8);
  trans_in<<<dim3(50, 32, 2), tb, 0, stream>>>(x, xflat);
  // in-MLP
  mgemm<1><<<dim3(1, 200), 256, 0, stream>>>(xflat, 128, xflat, 128, 128, wb + OFF_FC1, 128,
                                             fc1b, nullptr, bufA, 128, 128, 0);
  mgemm<4><<<dim3(2, 200), 256, 0, stream>>>(bufA, 128, bufA, 128, 128, wb + OFF_FC2, 128,
                                             fc2b, nullptr, hbuf, 256, 128, 0);

  for (int i = 0; i < 2; ++i) {
    ln_k<<<dim3(6400), 256, 0, stream>>>(hbuf, nw + i * 256, nb + i * 256, bufD, i);
    // up-proj, N=1024 -> xz = [xm | z]
    mgemm<0><<<dim3(8, 200), 256, 0, stream>>>(bufD, 256, bufD, 256, 256,
                                               wb + OFF_UP + (size_t)i * 262144, 256,
                                               upb + i * 1024, nullptr, xz, 1024, 256, 0);
    conv_k<<<dim3(NPOS), 512, 0, stream>>>(xz, cw + i * 2048, cb + i * 512, xab);
    // gates: A = [xa (512) | xm (512)], K=1024, N=256 -> bufD (bias included)
    mgemm<0><<<dim3(2, 200), 256, 0, stream>>>(xab, 512, xz, 1024, 512,
                                               wb + OFF_GW + (size_t)i * 262144, 1024,
                                               gbias + i * 256, nullptr, bufD, 256, 1024, 0);
    mlstm_k<<<dim3(NPOS), 128, 0, stream>>>(xab, xz, bufD, qw + i * 2048, kw + i * 2048,
                                            onw + i * 512, onb + i * 512, skp + i * 512);
    if (i == 0) {
      mgemm<2><<<dim3(2, 200), 256, 0, stream>>>(xab, 512, xab, 512, 512, wb + OFF_DW, 512,
                                                 dwb, nullptr, hbuf, 256, 512, 0);
    } else {
      mgemm<6><<<dim3(2, 200), 256, 0, stream>>>(xab, 512, xab, 512, 512, wb + OFF_DW + 131072,
                                                 512, dwb + 256, hbuf, hmirror, 256, 512, 1);
    }
  }

  // out-MLP
  mgemm<1><<<dim3(2, 200), 256, 0, stream>>>(hmirror, 256, hmirror, 256, 256, wb + OFF_OFC1, 256,
                                             ofc1b, nullptr, bufD, 256, 256, 0);
  mgemm<0><<<dim3(1, 200), 256, 0, stream>>>(bufD, 256, bufD, 256, 256, wb + OFF_OFC2, 256,
                                             ofc2b, nullptr, bufA, 128, 256, 0);
  trans_out<<<dim3(50, 32, 2), tb, 0, stream>>>(x, bufA, out);
}